// Round 17
// baseline (295.627 us; speedup 1.0000x reference)
//
#include <hip/hip_runtime.h>
#include <math.h>

#define SEQL 197
#define HD 768
#define NH 12
#define DHD 64
#define BATCH 64
#define OUTD 1000

typedef unsigned short ushort_t;
typedef __attribute__((ext_vector_type(8))) short bf16x8;
typedef __attribute__((ext_vector_type(4))) float f32x4;

static __device__ __forceinline__ unsigned short f2bf(float f) {
    union { float f; unsigned u; } v; v.f = f;
    unsigned r = v.u + 0x7fff + ((v.u >> 16) & 1);
    return (unsigned short)(r >> 16);
}

static __device__ __forceinline__ void gload16(const ushort_t* g, ushort_t* l) {
    __builtin_amdgcn_global_load_lds(
        (const __attribute__((address_space(1))) unsigned int*)g,
        (__attribute__((address_space(3))) unsigned int*)l, 16, 0, 0);
}

// bijective XCD-chunk swizzle (m204): consecutive vids land on the same XCD.
static __device__ __forceinline__ int xcd_chunk(int id, int nwg) {
    int xcd = id & 7, ii = id >> 3;
    int q = nwg >> 3, r = nwg & 7;
    return (xcd < r) ? (xcd * (q + 1) + ii) : (r * (q + 1) + (xcd - r) * q + ii);
}

// ---------------- init: positional table + cls row of tokens (+LN1 cls sums) ----
__global__ void k_init(const float* __restrict__ cls_tok, float* __restrict__ pos,
                       float* __restrict__ tok, float* __restrict__ stats) {
    int i = blockIdx.x * 256 + threadIdx.x;
    if (i < SEQL * HD) {
        int s = i / HD, d = i % HD;
        float f = (float)(d & ~1);
        float r = powf(10000.0f, -f / (float)HD);
        float a = (float)s * r;
        pos[i] = (d & 1) ? cosf(a) : sinf(a);
    } else {
        int j = i - SEQL * HD;
        if (j < BATCH * HD) {
            int b = j / HD, e = j % HD;
            float v = cls_tok[e] + ((e & 1) ? 1.0f : 0.0f);
            tok[(b * SEQL) * HD + e] = v;
            float sv = v, qv = v * v;
#pragma unroll
            for (int off = 32; off > 0; off >>= 1) {
                sv += __shfl_down(sv, off);
                qv += __shfl_down(qv, off);
            }
            if ((threadIdx.x & 63) == 0) {
                atomicAdd(&stats[2 * b], sv);
                atomicAdd(&stats[2 * b + 1], qv);
            }
        }
    }
}

// ---------------- all weight conversions (+ zero stats & logits) ----------------
__global__ void k_cvtAll(const float* __restrict__ W_map, const float* __restrict__ W_enc,
                         const float* __restrict__ Wq, const float* __restrict__ Wk,
                         const float* __restrict__ Wv,
                         ushort_t* __restrict__ WmT, ushort_t* __restrict__ WeT,
                         ushort_t* __restrict__ wt, float* __restrict__ stats,
                         float* __restrict__ logits) {
    int idx = blockIdx.x * 256 + threadIdx.x;
    if (blockIdx.x == 0 && threadIdx.x < 256) stats[threadIdx.x] = 0.f;
    if (idx < BATCH * OUTD) logits[idx] = 0.f;
    if (idx < 2 * 147456) {
        const float* W = (idx < 147456) ? W_map : W_enc;
        ushort_t* WT   = (idx < 147456) ? WmT : WeT;
        int i = (idx < 147456) ? idx : idx - 147456;
        int k = i / 192, nq = i % 192;
        float4 w = *(const float4*)&W[k * 768 + nq * 4];
        WT[(nq * 4 + 0) * 768 + k] = f2bf(w.x);
        WT[(nq * 4 + 1) * 768 + k] = f2bf(w.y);
        WT[(nq * 4 + 2) * 768 + k] = f2bf(w.z);
        WT[(nq * 4 + 3) * 768 + k] = f2bf(w.w);
    } else {
        int i = idx - 2 * 147456;
        if (i < 36864) {
            int dq = i & 15;
            int e  = (i >> 4) & 63;
            int h  = (i >> 10) % 12;
            int pj = i / 12288;
            const float* W = (pj == 0) ? Wq : (pj == 1) ? Wk : Wv;
            ushort4 o;
            o.x = f2bf(W[(h * 64 + dq * 4 + 0) * 64 + e]);
            o.y = f2bf(W[(h * 64 + dq * 4 + 1) * 64 + e]);
            o.z = f2bf(W[(h * 64 + dq * 4 + 2) * 64 + e]);
            o.w = f2bf(W[(h * 64 + dq * 4 + 3) * 64 + e]);
            *(ushort4*)&wt[(size_t)((pj * 12 + h) * 64 + e) * 64 + dq * 4] = o;
        }
    }
}

// ---------------- gather patches -> bf16 A [12544][768] ----------------
__global__ void k_prep_patches(const float* __restrict__ img, ushort_t* __restrict__ Ae) {
    int idx = blockIdx.x * 256 + threadIdx.x;       // 0 .. 12544*192
    int m = idx / 192, kq = idx % 192;
    int k0 = kq * 4;
    int c = k0 >> 8, rem = k0 & 255, ir = rem >> 4, jc = rem & 15;
    int b = m / 196, pi = m % 196;
    int pr = pi / 14, pc = pi % 14;
    float4 v = *(const float4*)&img[((b * 3 + c) * 224 + pr * 16 + ir) * 224 + pc * 16 + jc];
    ushort4 o;
    o.x = f2bf(v.x); o.y = f2bf(v.y); o.z = f2bf(v.z); o.w = f2bf(v.w);
    *(ushort4*)&Ae[m * 768 + k0] = o;
}

// ---------------- bf16 MFMA GEMM, 128x128 tile, BK=64, 4 waves, XCD-chunked ----
template <int MODE>
__launch_bounds__(256)
__global__ void k_gemm_bf16(const ushort_t* __restrict__ A, const ushort_t* __restrict__ Bt,
                            const float* __restrict__ bias, const float* __restrict__ pos,
                            float* __restrict__ out, int Mtot, float* __restrict__ stats,
                            int nwg) {
    __shared__ ushort_t As[128 * 64];
    __shared__ ushort_t Bs[128 * 64];
    __shared__ float redS[4][4];
    const int vid = xcd_chunk(blockIdx.x, nwg);
    const int m0 = (vid / 6) * 128;
    const int n0 = (vid % 6) * 128;
    const int tid = threadIdx.x;
    const int lane = tid & 63, wave = tid >> 6;
    const int wm = wave >> 1, wn = wave & 1;

    f32x4 acc[4][4];
#pragma unroll
    for (int i = 0; i < 4; ++i)
#pragma unroll
        for (int j = 0; j < 4; ++j)
#pragma unroll
            for (int r = 0; r < 4; ++r) acc[i][j][r] = 0.f;

    for (int kt = 0; kt < 12; ++kt) {
        const int k0 = kt * 64;
#pragma unroll
        for (int t = 0; t < 4; ++t) {
            int c = (wave << 2) | t;
            int o = c * 1024 + lane * 16;
            int row = o >> 7;
            int inner = o & 127;
            int col = (inner ^ ((row & 7) << 4)) >> 1;
            gload16(&A[(size_t)(m0 + row) * 768 + k0 + col], &As[c * 512]);
            gload16(&Bt[(size_t)(n0 + row) * 768 + k0 + col], &Bs[c * 512]);
        }
        __syncthreads();
#pragma unroll
        for (int ks = 0; ks < 2; ++ks) {
            const int cbyte = ks * 64 + (lane >> 4) * 16;
            bf16x8 af[4], bf[4];
#pragma unroll
            for (int mi = 0; mi < 4; ++mi) {
                int row = wm * 64 + mi * 16 + (lane & 15);
                af[mi] = *(const bf16x8*)((const char*)As + row * 128 + (cbyte ^ ((row & 7) << 4)));
            }
#pragma unroll
            for (int ni = 0; ni < 4; ++ni) {
                int n = wn * 64 + ni * 16 + (lane & 15);
                bf[ni] = *(const bf16x8*)((const char*)Bs + n * 128 + (cbyte ^ ((n & 7) << 4)));
            }
#pragma unroll
            for (int mi = 0; mi < 4; ++mi)
#pragma unroll
                for (int ni = 0; ni < 4; ++ni)
                    acc[mi][ni] = __builtin_amdgcn_mfma_f32_16x16x32_bf16(af[mi], bf[ni], acc[mi][ni], 0, 0, 0);
        }
        __syncthreads();
    }

    const int colb = n0 + wn * 64 + (lane & 15);
    const int rowb = m0 + wm * 64 + (lane >> 4) * 4;
    float s_lo = 0.f, q_lo = 0.f, s_hi = 0.f, q_hi = 0.f;
    const int bA = m0 / 196;
    const int mSplit = (bA + 1) * 196;
#pragma unroll
    for (int ni = 0; ni < 4; ++ni) {
        const int n = colb + ni * 16;
        const float bn = bias[n];
#pragma unroll
        for (int mi = 0; mi < 4; ++mi) {
#pragma unroll
            for (int r = 0; r < 4; ++r) {
                int m = rowb + mi * 16 + r;
                if (MODE == 0) {
                    int b = m / 196, s = 1 + m % 196;
                    float oval = acc[mi][ni][r] + bn + pos[s * HD + n];
                    out[((b * SEQL) + s) * HD + n] = oval;
                    if (m < mSplit) { s_lo += oval; q_lo += oval * oval; }
                    else            { s_hi += oval; q_hi += oval * oval; }
                } else {
                    if (m < Mtot) {
                        float* p = &out[(size_t)m * HD + n];
                        *p = *p + fmaxf(acc[mi][ni][r] + bn, 0.f);
                    }
                }
            }
        }
    }
    if (MODE == 0) {
#pragma unroll
        for (int off = 32; off > 0; off >>= 1) {
            s_lo += __shfl_down(s_lo, off);
            q_lo += __shfl_down(q_lo, off);
            s_hi += __shfl_down(s_hi, off);
            q_hi += __shfl_down(q_hi, off);
        }
        if (lane == 0) {
            redS[wave][0] = s_lo; redS[wave][1] = q_lo;
            redS[wave][2] = s_hi; redS[wave][3] = q_hi;
        }
        __syncthreads();
        if (tid == 0) {
            float a0 = 0.f, a1 = 0.f, a2 = 0.f, a3 = 0.f;
#pragma unroll
            for (int i = 0; i < 4; ++i) {
                a0 += redS[i][0]; a1 += redS[i][1];
                a2 += redS[i][2]; a3 += redS[i][3];
            }
            atomicAdd(&stats[2 * bA], a0);
            atomicAdd(&stats[2 * bA + 1], a1);
            int bB = bA + 1;
            if (bB < BATCH) {
                atomicAdd(&stats[2 * bB], a2);
                atomicAdd(&stats[2 * bB + 1], a3);
            }
        }
    }
}

// ---------------- FUSED v6: TWO (h,b) pairs per 1024-thread block --------------
// 16 waves; waves 0-7 = half 0 (h=hp), waves 8-15 = half 1 (h=hp+6), same b.
// Each half runs the round-15 body in its own 64KB LDS slice. One workgroup
// holds 16 waves (4/SIMD) -> intra-block latency hiding without needing two
// co-resident workgroups (which register accounting blocked in r13-r15).
__launch_bounds__(1024)
__global__ void k_qkvattn(const float* __restrict__ tok, float* __restrict__ stats,
                          const float* __restrict__ g1, const float* __restrict__ b1,
                          const ushort_t* __restrict__ wt,
                          const float* __restrict__ bq, const float* __restrict__ bk,
                          const float* __restrict__ bv, float* __restrict__ out) {
    const int hp = blockIdx.x, b = blockIdx.y;
    __shared__ __attribute__((aligned(16))) ushort_t sm[65536];   // 2 x (A16 | B16)
    __shared__ float rS[16], rS2[16];
    const int tid = threadIdx.x;
    const int wave = tid >> 6, lane = tid & 63;
    const int half = wave >> 3, w8 = wave & 7;
    const int h = hp + half * 6;
    const int l16 = lane & 15, l4 = lane >> 4;
    const int r0 = w8 * 32;
    const float inv_n = 1.0f / (float)(SEQL * HD);
    const float S1_ = stats[b * 2], S2_ = stats[b * 2 + 1];
    const float mu = S1_ * inv_n;
    const float rsg = rsqrtf(S2_ * inv_n - mu * mu + 1e-5f);
    ushort_t* A16 = sm + half * 32768;   // [256][64] XOR (X / Qtmp / K / P)
    ushort_t* B16 = A16 + 16384;         // [64][256] XOR (V^T)

    // ---- stage LN1(X) into OWN A16 rows (per half; wave w8 owns rows [32w8,+32)) ----
    {
        const int tid_h = tid & 511;
        const int row = tid_h >> 1, hw = tid_h & 1;
        if (row < SEQL) {
            const float* tp = &tok[((size_t)b * SEQL + row) * HD + h * 64 + hw * 32];
            const float* gp = &g1[(size_t)row * HD + h * 64 + hw * 32];
            const float* bp = &b1[(size_t)row * HD + h * 64 + hw * 32];
#pragma unroll
            for (int g = 0; g < 4; ++g) {
                float4 t0 = *(const float4*)&tp[g * 8];
                float4 t1 = *(const float4*)&tp[g * 8 + 4];
                float4 ga = *(const float4*)&gp[g * 8];
                float4 gb = *(const float4*)&gp[g * 8 + 4];
                float4 ba = *(const float4*)&bp[g * 8];
                float4 bb = *(const float4*)&bp[g * 8 + 4];
                bf16x8 o;
                o[0] = (short)f2bf((t0.x - mu) * rsg * ga.x + ba.x);
                o[1] = (short)f2bf((t0.y - mu) * rsg * ga.y + ba.y);
                o[2] = (short)f2bf((t0.z - mu) * rsg * ga.z + ba.z);
                o[3] = (short)f2bf((t0.w - mu) * rsg * ga.w + ba.w);
                o[4] = (short)f2bf((t1.x - mu) * rsg * gb.x + bb.x);
                o[5] = (short)f2bf((t1.y - mu) * rsg * gb.y + bb.y);
                o[6] = (short)f2bf((t1.z - mu) * rsg * gb.z + bb.z);
                o[7] = (short)f2bf((t1.w - mu) * rsg * gb.w + bb.w);
                int pc = (hw * 32 + g * 8) ^ ((row & 7) << 3);
                *(bf16x8*)&A16[row * 64 + pc] = o;
            }
        } else {
            bf16x8 z;
#pragma unroll
            for (int j = 0; j < 8; ++j) z[j] = 0;
#pragma unroll
            for (int g = 0; g < 4; ++g) {
                int pc = (hw * 32 + g * 8) ^ ((row & 7) << 3);
                *(bf16x8*)&A16[row * 64 + pc] = z;
            }
        }
    }

    // A fragments from own rows (wave-private; no barrier needed)
    bf16x8 af[2][2];
#pragma unroll
    for (int mi = 0; mi < 2; ++mi)
#pragma unroll
        for (int kk = 0; kk < 2; ++kk) {
            int row = r0 + mi * 16 + l16;
            af[mi][kk] = *(const bf16x8*)&A16[row * 64 + ((kk * 32 + l4 * 8) ^ ((row & 7) << 3))];
        }

#define PROJ_ACC(PJ, ACC)                                                                      \
    {                                                                                          \
        _Pragma("unroll") for (int ni = 0; ni < 4; ++ni) {                                     \
            const ushort_t* wr = &wt[(size_t)(((PJ) * 12 + h) * 64 + ni * 16 + l16) * 64];     \
            bf16x8 w0 = *(const bf16x8*)&wr[l4 * 8];                                           \
            bf16x8 w1 = *(const bf16x8*)&wr[32 + l4 * 8];                                      \
            _Pragma("unroll") for (int mi = 0; mi < 2; ++mi) {                                 \
                ACC[mi][ni] = __builtin_amdgcn_mfma_f32_16x16x32_bf16(af[mi][0], w0, ACC[mi][ni], 0, 0, 0); \
                ACC[mi][ni] = __builtin_amdgcn_mfma_f32_16x16x32_bf16(af[mi][1], w1, ACC[mi][ni], 0, 0, 0); \
            }                                                                                  \
        }                                                                                      \
    }

    f32x4 acc[2][4];
#define ZERO_ACC                                                                               \
    _Pragma("unroll") for (int mi = 0; mi < 2; ++mi)                                           \
        _Pragma("unroll") for (int ni = 0; ni < 4; ++ni) {                                     \
            acc[mi][ni][0] = 0.f; acc[mi][ni][1] = 0.f; acc[mi][ni][2] = 0.f; acc[mi][ni][3] = 0.f; }

    // ---- Q projection -> Qtmp bounce in OWN A16 rows ----
    ZERO_ACC;
    PROJ_ACC(0, acc);
#pragma unroll
    for (int ni = 0; ni < 4; ++ni) {
        float bn = bq[h * 64 + ni * 16 + l16];
#pragma unroll
        for (int mi = 0; mi < 2; ++mi)
#pragma unroll
            for (int r = 0; r < 4; ++r) {
                int row = r0 + mi * 16 + l4 * 4 + r;
                A16[row * 64 + ((ni * 16 + l16) ^ ((row & 7) << 3))] = f2bf(acc[mi][ni][r] + bn);
            }
    }
    bf16x8 qa[2][2];
#pragma unroll
    for (int mi = 0; mi < 2; ++mi)
#pragma unroll
        for (int kk = 0; kk < 2; ++kk) {
            int row = r0 + mi * 16 + l16;
            qa[mi][kk] = *(const bf16x8*)&A16[row * 64 + ((kk * 32 + l4 * 8) ^ ((row & 7) << 3))];
        }

    // ---- K projection -> OWN A16 rows ----
    ZERO_ACC;
    PROJ_ACC(1, acc);
#pragma unroll
    for (int ni = 0; ni < 4; ++ni) {
        float bn = bk[h * 64 + ni * 16 + l16];
#pragma unroll
        for (int mi = 0; mi < 2; ++mi)
#pragma unroll
            for (int r = 0; r < 4; ++r) {
                int t = r0 + mi * 16 + l4 * 4 + r;
                A16[t * 64 + ((ni * 16 + l16) ^ ((t & 7) << 3))] = f2bf(acc[mi][ni][r] + bn);
            }
    }

    // ---- V projection -> B16 (transposed, XOR, packed) ----
    ZERO_ACC;
    PROJ_ACC(2, acc);
#pragma unroll
    for (int ni = 0; ni < 4; ++ni) {
        float bn = bv[h * 64 + ni * 16 + l16];
#pragma unroll
        for (int mi = 0; mi < 2; ++mi) {
            int t4 = r0 + mi * 16 + l4 * 4;
            int e = ni * 16 + l16;
            ushort4 pkt;
            pkt.x = f2bf(acc[mi][ni][0] + bn);
            pkt.y = f2bf(acc[mi][ni][1] + bn);
            pkt.z = f2bf(acc[mi][ni][2] + bn);
            pkt.w = f2bf(acc[mi][ni][3] + bn);
            *(ushort4*)&B16[e * 256 + (t4 ^ ((e & 7) << 3))] = pkt;
        }
    }

    __syncthreads();   // barrier 1: K and V^T visible (both halves)

    // ---- QK^T over all 256 t ----
    f32x4 sa[2][16];
#pragma unroll
    for (int ni = 0; ni < 16; ++ni) {
        int t = ni * 16 + l16;
        bf16x8 k0 = *(const bf16x8*)&A16[t * 64 + ((l4 * 8) ^ ((t & 7) << 3))];
        bf16x8 k1 = *(const bf16x8*)&A16[t * 64 + ((32 + l4 * 8) ^ ((t & 7) << 3))];
#pragma unroll
        for (int mi = 0; mi < 2; ++mi) {
            f32x4 z;
            z[0] = 0.f; z[1] = 0.f; z[2] = 0.f; z[3] = 0.f;
            z = __builtin_amdgcn_mfma_f32_16x16x32_bf16(qa[mi][0], k0, z, 0, 0, 0);
            sa[mi][ni] = __builtin_amdgcn_mfma_f32_16x16x32_bf16(qa[mi][1], k1, z, 0, 0, 0);
        }
    }

    // ---- softmax per q-row, NO max subtraction ----
    float l_s[2][4];
#pragma unroll
    for (int mi = 0; mi < 2; ++mi)
#pragma unroll
        for (int r = 0; r < 4; ++r) {
            float rsum = 0.f;
#pragma unroll
            for (int ni = 0; ni < 16; ++ni) {
                float p = (ni * 16 + l16 < SEQL) ? __expf(sa[mi][ni][r] * 0.125f) : 0.f;
                sa[mi][ni][r] = p;
                rsum += p;
            }
            rsum += __shfl_xor(rsum, 1);
            rsum += __shfl_xor(rsum, 2);
            rsum += __shfl_xor(rsum, 4);
            rsum += __shfl_xor(rsum, 8);
            l_s[mi][r] = rsum;
        }

    __syncthreads();   // barrier 2: A16 free for P (both halves)

    // ---- PV in 4 chunks of 64 t ----
    f32x4 oacc[2][4];
#pragma unroll
    for (int mi = 0; mi < 2; ++mi)
#pragma unroll
        for (int ne = 0; ne < 4; ++ne) {
            oacc[mi][ne][0] = 0.f; oacc[mi][ne][1] = 0.f;
            oacc[mi][ne][2] = 0.f; oacc[mi][ne][3] = 0.f;
        }

    for (int c = 0; c < 4; ++c) {
#pragma unroll
        for (int j = 0; j < 4; ++j)
#pragma unroll
            for (int mi = 0; mi < 2; ++mi)
#pragma unroll
                for (int r = 0; r < 4; ++r) {
                    int row = r0 + mi * 16 + l4 * 4 + r;
                    A16[row * 64 + ((j * 16 + l16) ^ ((row & 7) << 3))] = f2bf(sa[mi][c * 4 + j][r]);
                }
        bf16x8 pa[2][2];
#pragma unroll
        for (int mi = 0; mi < 2; ++mi)
#pragma unroll
            for (int kk = 0; kk < 2; ++kk) {
                int row = r0 + mi * 16 + l16;
                pa[mi][kk] = *(const bf16x8*)&A16[row * 64 + ((kk * 32 + l4 * 8) ^ ((row & 7) << 3))];
            }
#pragma unroll
        for (int ne = 0; ne < 4; ++ne) {
            int e = ne * 16 + l16;
            bf16x8 v0 = *(const bf16x8*)&B16[e * 256 + ((c * 64 + l4 * 8) ^ ((e & 7) << 3))];
            bf16x8 v1 = *(const bf16x8*)&B16[e * 256 + ((c * 64 + 32 + l4 * 8) ^ ((e & 7) << 3))];
#pragma unroll
            for (int mi = 0; mi < 2; ++mi) {
                oacc[mi][ne] = __builtin_amdgcn_mfma_f32_16x16x32_bf16(pa[mi][0], v0, oacc[mi][ne], 0, 0, 0);
                oacc[mi][ne] = __builtin_amdgcn_mfma_f32_16x16x32_bf16(pa[mi][1], v1, oacc[mi][ne], 0, 0, 0);
            }
        }
    }

    // ---- epilogue: O staged in own half's 64KB -> coalesced residual ----
    __syncthreads();   // barrier 3 (both halves done with A16/B16)
    float* Osm = (float*)A16 + w8 * 2048;   // per-wave [32][64] f32, spans half's region
#pragma unroll
    for (int mi = 0; mi < 2; ++mi)
#pragma unroll
        for (int r = 0; r < 4; ++r) {
            float inv = 1.0f / l_s[mi][r];
            int rl = mi * 16 + l4 * 4 + r;
#pragma unroll
            for (int ne = 0; ne < 4; ++ne)
                Osm[rl * 64 + ((ne * 16 + l16) ^ ((rl & 3) << 4))] = oacc[mi][ne][r] * inv;
        }
    float psum = 0.f, psq = 0.f;
#pragma unroll
    for (int it = 0; it < 8; ++it) {
        int rl = it * 4 + l4;
        int row = r0 + rl;
        if (row < SEQL) {
            size_t off = ((size_t)b * SEQL + row) * HD + h * 64 + l16 * 4;
            float4 ov = *(float4*)&Osm[rl * 64 + ((l16 * 4) ^ ((rl & 3) << 4))];
            float4 tv = *(const float4*)&tok[off];
            float4 o;
            o.x = ov.x + tv.x; o.y = ov.y + tv.y;
            o.z = ov.z + tv.z; o.w = ov.w + tv.w;
            *(float4*)&out[off] = o;
            psum += o.x + o.y + o.z + o.w;
            psq  += o.x * o.x + o.y * o.y + o.z * o.z + o.w * o.w;
        }
    }
#pragma unroll
    for (int off = 32; off > 0; off >>= 1) {
        psum += __shfl_down(psum, off);
        psq += __shfl_down(psq, off);
    }
    if (lane == 0) { rS[wave] = psum; rS2[wave] = psq; }
    __syncthreads();
    if (tid == 0) {
        float S = 0.f, S2 = 0.f;
#pragma unroll
        for (int i = 0; i < 16; ++i) { S += rS[i]; S2 += rS2[i]; }
        atomicAdd(&stats[128 + 2 * b], S);
        atomicAdd(&stats[129 + 2 * b], S2);
    }
#undef PROJ_ACC
#undef ZERO_ACC
}

// ---------------- LN2 apply (finalizes stats from raw sums) -> bf16 ----------------
__global__ void k_ln2apply(const float* __restrict__ outb, const float* __restrict__ stats,
                           const float* __restrict__ g2, const float* __restrict__ b2,
                           ushort_t* __restrict__ x) {
    int i = blockIdx.x * 256 + threadIdx.x;
    if (i >= BATCH * SEQL * HD / 4) return;
    int e4 = i * 4;
    int m = e4 / HD, kk = e4 % HD;
    int b = m / SEQL, s = m % SEQL;
    const float inv_n = 1.0f / (float)(SEQL * HD);
    float S = stats[128 + 2 * b], S2 = stats[129 + 2 * b];
    float mu = S * inv_n;
    float rsg = rsqrtf(S2 * inv_n - mu * mu + 1e-5f);
    float4 t = *(const float4*)&outb[e4];
    float4 g = *(const float4*)&g2[s * HD + kk];
    float4 bb = *(const float4*)&b2[s * HD + kk];
    ushort4 o;
    o.x = f2bf((t.x - mu) * rsg * g.x + bb.x);
    o.y = f2bf((t.y - mu) * rsg * g.y + bb.y);
    o.z = f2bf((t.z - mu) * rsg * g.z + bb.z);
    o.w = f2bf((t.w - mu) * rsg * g.w + bb.w);
    *(ushort4*)&x[e4] = o;
}

// ---------------- classifier logits: partial dots over e-chunks (4x parallel) ----
__launch_bounds__(256)
__global__ void k_logits(const float* __restrict__ out, const float* __restrict__ Wo,
                         float* __restrict__ logits) {
    const int eg = blockIdx.x, b = blockIdx.y, tid = threadIdx.x;
    __shared__ float cls[192];
    if (tid < 48)
        *(float4*)&cls[tid * 4] = *(const float4*)&out[(size_t)(b * SEQL) * HD + eg * 192 + tid * 4];
    __syncthreads();
    const int o0 = tid * 4;
    if (o0 < OUTD) {
        float4 acc = {0.f, 0.f, 0.f, 0.f};
        const float* wbase = &Wo[(size_t)eg * 192 * OUTD + o0];
#pragma unroll 4
        for (int e = 0; e < 192; ++e) {
            float c = cls[e];
            float4 w = *(const float4*)&wbase[(size_t)e * OUTD];
            acc.x += c * w.x;
            acc.y += c * w.y;
            acc.z += c * w.z;
            acc.w += c * w.w;
        }
        atomicAdd(&logits[b * OUTD + o0 + 0], acc.x);
        atomicAdd(&logits[b * OUTD + o0 + 1], acc.y);
        atomicAdd(&logits[b * OUTD + o0 + 2], acc.z);
        atomicAdd(&logits[b * OUTD + o0 + 3], acc.w);
    }
}

// ---------------- head softmax (reads logits + bias) ----------------
__launch_bounds__(256)
__global__ void k_head_sm(const float* __restrict__ logits, const float* __restrict__ bo,
                          float* __restrict__ dout) {
    const int b = blockIdx.x, tid = threadIdx.x;
    __shared__ float red[256];
    const int o0 = tid * 4;
    const bool ok = (o0 < OUTD);
    float4 acc = {0.f, 0.f, 0.f, 0.f};
    if (ok) {
        float4 lg = *(const float4*)&logits[b * OUTD + o0];
        float4 bb = *(const float4*)&bo[o0];
        acc.x = lg.x + bb.x; acc.y = lg.y + bb.y;
        acc.z = lg.z + bb.z; acc.w = lg.w + bb.w;
    }
    float mx = ok ? fmaxf(fmaxf(acc.x, acc.y), fmaxf(acc.z, acc.w)) : -INFINITY;
    red[tid] = mx;
    __syncthreads();
    for (int s = 128; s > 0; s >>= 1) {
        if (tid < s) red[tid] = fmaxf(red[tid], red[tid + s]);
        __syncthreads();
    }
    float M = red[0];
    __syncthreads();
    float4 p = {0.f, 0.f, 0.f, 0.f};
    float ls = 0.f;
    if (ok) {
        p.x = expf(acc.x - M);
        p.y = expf(acc.y - M);
        p.z = expf(acc.z - M);
        p.w = expf(acc.w - M);
        ls = p.x + p.y + p.z + p.w;
    }
    red[tid] = ls;
    __syncthreads();
    for (int s = 128; s > 0; s >>= 1) {
        if (tid < s) red[tid] += red[tid + s];
        __syncthreads();
    }
    float inv = 1.0f / red[0];
    if (ok) {
        p.x *= inv; p.y *= inv; p.z *= inv; p.w *= inv;
        *(float4*)&dout[b * OUTD + o0] = p;
    }
}

extern "C" void kernel_launch(void* const* d_in, const int* in_sizes, int n_in,
                              void* d_out, int out_size, void* d_ws, size_t ws_size,
                              hipStream_t stream) {
    const float* images  = (const float*)d_in[0];
    const float* W_map   = (const float*)d_in[1];
    const float* b_map   = (const float*)d_in[2];
    const float* cls_tok = (const float*)d_in[3];
    const float* ln1_g   = (const float*)d_in[4];
    const float* ln1_b   = (const float*)d_in[5];
    const float* Wq      = (const float*)d_in[6];
    const float* bq      = (const float*)d_in[7];
    const float* Wk      = (const float*)d_in[8];
    const float* bk      = (const float*)d_in[9];
    const float* Wv      = (const float*)d_in[10];
    const float* bv      = (const float*)d_in[11];
    const float* ln2_g   = (const float*)d_in[12];
    const float* ln2_b   = (const float*)d_in[13];
    const float* W_enc   = (const float*)d_in[14];
    const float* b_enc   = (const float*)d_in[15];
    const float* W_out   = (const float*)d_in[16];
    const float* b_out   = (const float*)d_in[17];

    float* ws = (float*)d_ws;
    const size_t BIG = (size_t)BATCH * SEQL * HD;     // 9,682,944

    float* pos   = ws;
    float* tok   = ws + 151552;
    float* outb  = tok + BIG;
    float* stats = outb + BIG;                        // 256 f32
    ushort_t* wtq = (ushort_t*)(stats + 256);         // bf16 147,456
    ushort_t* Ae  = wtq + 147456;                     // bf16 [12672][768]
    ushort_t* WmT = Ae + (size_t)12672 * 768;         // bf16 [768][768]
    ushort_t* WeT = WmT + (size_t)768 * 768;          // bf16 [768][768]
    float* logits = (float*)(WeT + (size_t)768 * 768);// 64,000 f32
    ushort_t* Ae2 = Ae;

    k_cvtAll<<<1296, 256, 0, stream>>>(W_map, W_enc, Wq, Wk, Wv, WmT, WeT, wtq, stats, logits);
    k_init<<<783, 256, 0, stream>>>(cls_tok, pos, tok, stats);
    k_prep_patches<<<9408, 256, 0, stream>>>(images, Ae);
    k_gemm_bf16<0><<<588, 256, 0, stream>>>(Ae, WmT, b_map, pos, tok, 12544, stats, 588);
    k_qkvattn<<<dim3(6, 64), 1024, 0, stream>>>(tok, stats, ln1_g, ln1_b, wtq, bq, bk, bv, outb);
    k_ln2apply<<<9456, 256, 0, stream>>>(outb, stats, ln2_g, ln2_b, Ae2);
    k_gemm_bf16<1><<<594, 256, 0, stream>>>(Ae2, WeT, b_enc, pos, outb, 12608, stats, 594);
    k_logits<<<dim3(4, 64), 256, 0, stream>>>(outb, W_out, logits);
    k_head_sm<<<64, 256, 0, stream>>>(logits, b_out, (float*)d_out);
}

// Round 18
// 233.810 us; speedup vs baseline: 1.2644x; 1.2644x over previous
//
#include <hip/hip_runtime.h>
#include <math.h>

#define SEQL 197
#define HD 768
#define NH 12
#define DHD 64
#define BATCH 64
#define OUTD 1000

typedef unsigned short ushort_t;
typedef __attribute__((ext_vector_type(8))) short bf16x8;
typedef __attribute__((ext_vector_type(4))) float f32x4;

static __device__ __forceinline__ unsigned short f2bf(float f) {
    union { float f; unsigned u; } v; v.f = f;
    unsigned r = v.u + 0x7fff + ((v.u >> 16) & 1);
    return (unsigned short)(r >> 16);
}

static __device__ __forceinline__ void gload16(const ushort_t* g, ushort_t* l) {
    __builtin_amdgcn_global_load_lds(
        (const __attribute__((address_space(1))) unsigned int*)g,
        (__attribute__((address_space(3))) unsigned int*)l, 16, 0, 0);
}

// bijective XCD-chunk swizzle (m204) — used by the GEMMs only (A-panel L2 reuse).
static __device__ __forceinline__ int xcd_chunk(int id, int nwg) {
    int xcd = id & 7, ii = id >> 3;
    int q = nwg >> 3, r = nwg & 7;
    return (xcd < r) ? (xcd * (q + 1) + ii) : (r * (q + 1) + (xcd - r) * q + ii);
}

// ---------------- merged prologue: weight cvts + zeroing + pos/cls + patches ----
// block ranges: [0,1296) cvt+zero | [1296,2079) pos/cls | 2079 S_cls | [2080,11488) patches
#define NB_CVT  1296
#define NB_INIT 783
__global__ void k_prep(const float* __restrict__ W_map, const float* __restrict__ W_enc,
                       const float* __restrict__ Wq, const float* __restrict__ Wk,
                       const float* __restrict__ Wv, const float* __restrict__ cls_tok,
                       const float* __restrict__ img,
                       ushort_t* __restrict__ WmT, ushort_t* __restrict__ WeT,
                       ushort_t* __restrict__ wt, float* __restrict__ stats,
                       float* __restrict__ logits, float* __restrict__ pos,
                       float* __restrict__ tok, ushort_t* __restrict__ Ae) {
    const int bx = blockIdx.x, tid = threadIdx.x;
    if (bx < NB_CVT) {
        int idx = bx * 256 + tid;
        if (bx == 0) { stats[tid] = 0.f; }                 // zero stats[0..256)
        if (idx < BATCH * OUTD) logits[idx] = 0.f;
        if (idx < 2 * 147456) {
            const float* W = (idx < 147456) ? W_map : W_enc;
            ushort_t* WT   = (idx < 147456) ? WmT : WeT;
            int i = (idx < 147456) ? idx : idx - 147456;
            int k = i / 192, nq = i % 192;
            float4 w = *(const float4*)&W[k * 768 + nq * 4];
            WT[(nq * 4 + 0) * 768 + k] = f2bf(w.x);
            WT[(nq * 4 + 1) * 768 + k] = f2bf(w.y);
            WT[(nq * 4 + 2) * 768 + k] = f2bf(w.z);
            WT[(nq * 4 + 3) * 768 + k] = f2bf(w.w);
        } else {
            int i = idx - 2 * 147456;
            if (i < 36864) {
                int dq = i & 15;
                int e  = (i >> 4) & 63;
                int h  = (i >> 10) % 12;
                int pj = i / 12288;
                const float* W = (pj == 0) ? Wq : (pj == 1) ? Wk : Wv;
                ushort4 o;
                o.x = f2bf(W[(h * 64 + dq * 4 + 0) * 64 + e]);
                o.y = f2bf(W[(h * 64 + dq * 4 + 1) * 64 + e]);
                o.z = f2bf(W[(h * 64 + dq * 4 + 2) * 64 + e]);
                o.w = f2bf(W[(h * 64 + dq * 4 + 3) * 64 + e]);
                *(ushort4*)&wt[(size_t)((pj * 12 + h) * 64 + e) * 64 + dq * 4] = o;
            }
        }
    } else if (bx < NB_CVT + NB_INIT) {
        int i = (bx - NB_CVT) * 256 + tid;
        if (i < SEQL * HD) {
            int s = i / HD, d = i % HD;
            float f = (float)(d & ~1);
            float r = powf(10000.0f, -f / (float)HD);
            float a = (float)s * r;
            pos[i] = (d & 1) ? cosf(a) : sinf(a);
        } else {
            int j = i - SEQL * HD;   // < BATCH*HD by construction (783*256 = 200448)
            int b = j / HD, e = j % HD;
            tok[(b * SEQL) * HD + e] = cls_tok[e] + ((e & 1) ? 1.0f : 0.0f);
        }
    } else if (bx == NB_CVT + NB_INIT) {
        // batch-invariant cls-row LN1 sums -> stats[256], stats[257]
        __shared__ float rs[4], rs2[4];
        float s = 0.f, s2 = 0.f;
#pragma unroll
        for (int j = 0; j < 3; ++j) {
            int e = tid * 3 + j;
            float v = cls_tok[e] + ((e & 1) ? 1.0f : 0.0f);
            s += v; s2 += v * v;
        }
#pragma unroll
        for (int off = 32; off > 0; off >>= 1) {
            s += __shfl_down(s, off);
            s2 += __shfl_down(s2, off);
        }
        int lane = tid & 63, w = tid >> 6;
        if (lane == 0) { rs[w] = s; rs2[w] = s2; }
        __syncthreads();
        if (tid == 0) {
            float S = 0.f, S2 = 0.f;
#pragma unroll
            for (int i = 0; i < 4; ++i) { S += rs[i]; S2 += rs2[i]; }
            stats[256] = S;
            stats[257] = S2;
        }
    } else {
        int idx = (bx - (NB_CVT + NB_INIT + 1)) * 256 + tid;   // patches
        int m = idx / 192, kq = idx % 192;
        int k0 = kq * 4;
        int c = k0 >> 8, rem = k0 & 255, ir = rem >> 4, jc = rem & 15;
        int b = m / 196, pi = m % 196;
        int pr = pi / 14, pc = pi % 14;
        float4 v = *(const float4*)&img[((b * 3 + c) * 224 + pr * 16 + ir) * 224 + pc * 16 + jc];
        ushort4 o;
        o.x = f2bf(v.x); o.y = f2bf(v.y); o.z = f2bf(v.z); o.w = f2bf(v.w);
        *(ushort4*)&Ae[m * 768 + k0] = o;
    }
}

// ---------------- bf16 MFMA GEMM, 128x128 tile, BK=64, 4 waves, XCD-chunked ----
template <int MODE>
__launch_bounds__(256)
__global__ void k_gemm_bf16(const ushort_t* __restrict__ A, const ushort_t* __restrict__ Bt,
                            const float* __restrict__ bias, const float* __restrict__ pos,
                            float* __restrict__ out, int Mtot, float* __restrict__ stats,
                            int nwg) {
    __shared__ ushort_t As[128 * 64];
    __shared__ ushort_t Bs[128 * 64];
    __shared__ float redS[4][4];
    const int vid = xcd_chunk(blockIdx.x, nwg);
    const int m0 = (vid / 6) * 128;
    const int n0 = (vid % 6) * 128;
    const int tid = threadIdx.x;
    const int lane = tid & 63, wave = tid >> 6;
    const int wm = wave >> 1, wn = wave & 1;

    f32x4 acc[4][4];
#pragma unroll
    for (int i = 0; i < 4; ++i)
#pragma unroll
        for (int j = 0; j < 4; ++j)
#pragma unroll
            for (int r = 0; r < 4; ++r) acc[i][j][r] = 0.f;

    for (int kt = 0; kt < 12; ++kt) {
        const int k0 = kt * 64;
#pragma unroll
        for (int t = 0; t < 4; ++t) {
            int c = (wave << 2) | t;
            int o = c * 1024 + lane * 16;
            int row = o >> 7;
            int inner = o & 127;
            int col = (inner ^ ((row & 7) << 4)) >> 1;
            gload16(&A[(size_t)(m0 + row) * 768 + k0 + col], &As[c * 512]);
            gload16(&Bt[(size_t)(n0 + row) * 768 + k0 + col], &Bs[c * 512]);
        }
        __syncthreads();
#pragma unroll
        for (int ks = 0; ks < 2; ++ks) {
            const int cbyte = ks * 64 + (lane >> 4) * 16;
            bf16x8 af[4], bf[4];
#pragma unroll
            for (int mi = 0; mi < 4; ++mi) {
                int row = wm * 64 + mi * 16 + (lane & 15);
                af[mi] = *(const bf16x8*)((const char*)As + row * 128 + (cbyte ^ ((row & 7) << 4)));
            }
#pragma unroll
            for (int ni = 0; ni < 4; ++ni) {
                int n = wn * 64 + ni * 16 + (lane & 15);
                bf[ni] = *(const bf16x8*)((const char*)Bs + n * 128 + (cbyte ^ ((n & 7) << 4)));
            }
#pragma unroll
            for (int mi = 0; mi < 4; ++mi)
#pragma unroll
                for (int ni = 0; ni < 4; ++ni)
                    acc[mi][ni] = __builtin_amdgcn_mfma_f32_16x16x32_bf16(af[mi], bf[ni], acc[mi][ni], 0, 0, 0);
        }
        __syncthreads();
    }

    const int colb = n0 + wn * 64 + (lane & 15);
    const int rowb = m0 + wm * 64 + (lane >> 4) * 4;
    float s_lo = 0.f, q_lo = 0.f, s_hi = 0.f, q_hi = 0.f;
    const int bA = m0 / 196;
    const int mSplit = (bA + 1) * 196;
#pragma unroll
    for (int ni = 0; ni < 4; ++ni) {
        const int n = colb + ni * 16;
        const float bn = bias[n];
#pragma unroll
        for (int mi = 0; mi < 4; ++mi) {
#pragma unroll
            for (int r = 0; r < 4; ++r) {
                int m = rowb + mi * 16 + r;
                if (MODE == 0) {
                    int b = m / 196, s = 1 + m % 196;
                    float oval = acc[mi][ni][r] + bn + pos[s * HD + n];
                    out[((b * SEQL) + s) * HD + n] = oval;
                    if (m < mSplit) { s_lo += oval; q_lo += oval * oval; }
                    else            { s_hi += oval; q_hi += oval * oval; }
                } else {
                    if (m < Mtot) {
                        float* p = &out[(size_t)m * HD + n];
                        *p = *p + fmaxf(acc[mi][ni][r] + bn, 0.f);
                    }
                }
            }
        }
    }
    if (MODE == 0) {
#pragma unroll
        for (int off = 32; off > 0; off >>= 1) {
            s_lo += __shfl_down(s_lo, off);
            q_lo += __shfl_down(q_lo, off);
            s_hi += __shfl_down(s_hi, off);
            q_hi += __shfl_down(q_hi, off);
        }
        if (lane == 0) {
            redS[wave][0] = s_lo; redS[wave][1] = q_lo;
            redS[wave][2] = s_hi; redS[wave][3] = q_hi;
        }
        __syncthreads();
        if (tid == 0) {
            float a0 = 0.f, a1 = 0.f, a2 = 0.f, a3 = 0.f;
#pragma unroll
            for (int i = 0; i < 4; ++i) {
                a0 += redS[i][0]; a1 += redS[i][1];
                a2 += redS[i][2]; a3 += redS[i][3];
            }
            atomicAdd(&stats[2 * bA], a0);
            atomicAdd(&stats[2 * bA + 1], a1);
            int bB = bA + 1;
            if (bB < BATCH) {
                atomicAdd(&stats[2 * bB], a2);
                atomicAdd(&stats[2 * bB + 1], a3);
            }
        }
    }
}

// ---------------- FUSED: LN1 + QKV + attention + residual (round-15 body) ------
// grid dim3(12,64), default dispatch order (h-major) — best measured tok locality.
__launch_bounds__(512, 2)
__global__ void k_qkvattn(const float* __restrict__ tok, float* __restrict__ stats,
                          const float* __restrict__ g1, const float* __restrict__ b1,
                          const ushort_t* __restrict__ wt,
                          const float* __restrict__ bq, const float* __restrict__ bk,
                          const float* __restrict__ bv, float* __restrict__ out) {
    const int h = blockIdx.x, b = blockIdx.y;
    __shared__ __attribute__((aligned(16))) ushort_t sm[32768];   // A16 | B16
    __shared__ float rS[8], rS2[8];
    const int tid = threadIdx.x;
    const int wave = tid >> 6, lane = tid & 63;
    const int l16 = lane & 15, l4 = lane >> 4;
    const int r0 = wave * 32;
    const float inv_n = 1.0f / (float)(SEQL * HD);
    const float S1_ = stats[b * 2] + stats[256];      // patch sums + batch-invariant cls sums
    const float S2_ = stats[b * 2 + 1] + stats[257];
    const float mu = S1_ * inv_n;
    const float rsg = rsqrtf(S2_ * inv_n - mu * mu + 1e-5f);
    ushort_t* A16 = sm;            // [256][64] XOR (X / Qtmp / K / P)
    ushort_t* B16 = sm + 16384;    // [64][256] XOR (V^T)

    // ---- stage LN1(X) into OWN A16 rows ----
    {
        const int row = tid >> 1, hw = tid & 1;
        if (row < SEQL) {
            const float* tp = &tok[((size_t)b * SEQL + row) * HD + h * 64 + hw * 32];
            const float* gp = &g1[(size_t)row * HD + h * 64 + hw * 32];
            const float* bp = &b1[(size_t)row * HD + h * 64 + hw * 32];
#pragma unroll
            for (int g = 0; g < 4; ++g) {
                float4 t0 = *(const float4*)&tp[g * 8];
                float4 t1 = *(const float4*)&tp[g * 8 + 4];
                float4 ga = *(const float4*)&gp[g * 8];
                float4 gb = *(const float4*)&gp[g * 8 + 4];
                float4 ba = *(const float4*)&bp[g * 8];
                float4 bb = *(const float4*)&bp[g * 8 + 4];
                bf16x8 o;
                o[0] = (short)f2bf((t0.x - mu) * rsg * ga.x + ba.x);
                o[1] = (short)f2bf((t0.y - mu) * rsg * ga.y + ba.y);
                o[2] = (short)f2bf((t0.z - mu) * rsg * ga.z + ba.z);
                o[3] = (short)f2bf((t0.w - mu) * rsg * ga.w + ba.w);
                o[4] = (short)f2bf((t1.x - mu) * rsg * gb.x + bb.x);
                o[5] = (short)f2bf((t1.y - mu) * rsg * gb.y + bb.y);
                o[6] = (short)f2bf((t1.z - mu) * rsg * gb.z + bb.z);
                o[7] = (short)f2bf((t1.w - mu) * rsg * gb.w + bb.w);
                int pc = (hw * 32 + g * 8) ^ ((row & 7) << 3);
                *(bf16x8*)&A16[row * 64 + pc] = o;
            }
        } else {
            bf16x8 z;
#pragma unroll
            for (int j = 0; j < 8; ++j) z[j] = 0;
#pragma unroll
            for (int g = 0; g < 4; ++g) {
                int pc = (hw * 32 + g * 8) ^ ((row & 7) << 3);
                *(bf16x8*)&A16[row * 64 + pc] = z;
            }
        }
    }

    // A fragments from own rows (wave-private; no barrier needed)
    bf16x8 af[2][2];
#pragma unroll
    for (int mi = 0; mi < 2; ++mi)
#pragma unroll
        for (int kk = 0; kk < 2; ++kk) {
            int row = r0 + mi * 16 + l16;
            af[mi][kk] = *(const bf16x8*)&A16[row * 64 + ((kk * 32 + l4 * 8) ^ ((row & 7) << 3))];
        }

#define PROJ_ACC(PJ, ACC)                                                                      \
    {                                                                                          \
        _Pragma("unroll") for (int ni = 0; ni < 4; ++ni) {                                     \
            const ushort_t* wr = &wt[(size_t)(((PJ) * 12 + h) * 64 + ni * 16 + l16) * 64];     \
            bf16x8 w0 = *(const bf16x8*)&wr[l4 * 8];                                           \
            bf16x8 w1 = *(const bf16x8*)&wr[32 + l4 * 8];                                      \
            _Pragma("unroll") for (int mi = 0; mi < 2; ++mi) {                                 \
                ACC[mi][ni] = __builtin_amdgcn_mfma_f32_16x16x32_bf16(af[mi][0], w0, ACC[mi][ni], 0, 0, 0); \
                ACC[mi][ni] = __builtin_amdgcn_mfma_f32_16x16x32_bf16(af[mi][1], w1, ACC[mi][ni], 0, 0, 0); \
            }                                                                                  \
        }                                                                                      \
    }

    f32x4 acc[2][4];
#define ZERO_ACC                                                                               \
    _Pragma("unroll") for (int mi = 0; mi < 2; ++mi)                                           \
        _Pragma("unroll") for (int ni = 0; ni < 4; ++ni) {                                     \
            acc[mi][ni][0] = 0.f; acc[mi][ni][1] = 0.f; acc[mi][ni][2] = 0.f; acc[mi][ni][3] = 0.f; }

    // ---- Q projection -> Qtmp bounce in OWN A16 rows ----
    ZERO_ACC;
    PROJ_ACC(0, acc);
#pragma unroll
    for (int ni = 0; ni < 4; ++ni) {
        float bn = bq[h * 64 + ni * 16 + l16];
#pragma unroll
        for (int mi = 0; mi < 2; ++mi)
#pragma unroll
            for (int r = 0; r < 4; ++r) {
                int row = r0 + mi * 16 + l4 * 4 + r;
                A16[row * 64 + ((ni * 16 + l16) ^ ((row & 7) << 3))] = f2bf(acc[mi][ni][r] + bn);
            }
    }
    bf16x8 qa[2][2];
#pragma unroll
    for (int mi = 0; mi < 2; ++mi)
#pragma unroll
        for (int kk = 0; kk < 2; ++kk) {
            int row = r0 + mi * 16 + l16;
            qa[mi][kk] = *(const bf16x8*)&A16[row * 64 + ((kk * 32 + l4 * 8) ^ ((row & 7) << 3))];
        }

    // ---- K projection -> OWN A16 rows ----
    ZERO_ACC;
    PROJ_ACC(1, acc);
#pragma unroll
    for (int ni = 0; ni < 4; ++ni) {
        float bn = bk[h * 64 + ni * 16 + l16];
#pragma unroll
        for (int mi = 0; mi < 2; ++mi)
#pragma unroll
            for (int r = 0; r < 4; ++r) {
                int t = r0 + mi * 16 + l4 * 4 + r;
                A16[t * 64 + ((ni * 16 + l16) ^ ((t & 7) << 3))] = f2bf(acc[mi][ni][r] + bn);
            }
    }

    // ---- V projection -> B16 (transposed, XOR, packed) ----
    ZERO_ACC;
    PROJ_ACC(2, acc);
#pragma unroll
    for (int ni = 0; ni < 4; ++ni) {
        float bn = bv[h * 64 + ni * 16 + l16];
#pragma unroll
        for (int mi = 0; mi < 2; ++mi) {
            int t4 = r0 + mi * 16 + l4 * 4;
            int e = ni * 16 + l16;
            ushort4 pkt;
            pkt.x = f2bf(acc[mi][ni][0] + bn);
            pkt.y = f2bf(acc[mi][ni][1] + bn);
            pkt.z = f2bf(acc[mi][ni][2] + bn);
            pkt.w = f2bf(acc[mi][ni][3] + bn);
            *(ushort4*)&B16[e * 256 + (t4 ^ ((e & 7) << 3))] = pkt;
        }
    }

    __syncthreads();   // barrier 1: K and V^T visible

    // ---- QK^T over all 256 t ----
    f32x4 sa[2][16];
#pragma unroll
    for (int ni = 0; ni < 16; ++ni) {
        int t = ni * 16 + l16;
        bf16x8 k0 = *(const bf16x8*)&A16[t * 64 + ((l4 * 8) ^ ((t & 7) << 3))];
        bf16x8 k1 = *(const bf16x8*)&A16[t * 64 + ((32 + l4 * 8) ^ ((t & 7) << 3))];
#pragma unroll
        for (int mi = 0; mi < 2; ++mi) {
            f32x4 z;
            z[0] = 0.f; z[1] = 0.f; z[2] = 0.f; z[3] = 0.f;
            z = __builtin_amdgcn_mfma_f32_16x16x32_bf16(qa[mi][0], k0, z, 0, 0, 0);
            sa[mi][ni] = __builtin_amdgcn_mfma_f32_16x16x32_bf16(qa[mi][1], k1, z, 0, 0, 0);
        }
    }

    // ---- softmax per q-row, NO max subtraction ----
    float l_s[2][4];
#pragma unroll
    for (int mi = 0; mi < 2; ++mi)
#pragma unroll
        for (int r = 0; r < 4; ++r) {
            float rsum = 0.f;
#pragma unroll
            for (int ni = 0; ni < 16; ++ni) {
                float p = (ni * 16 + l16 < SEQL) ? __expf(sa[mi][ni][r] * 0.125f) : 0.f;
                sa[mi][ni][r] = p;
                rsum += p;
            }
            rsum += __shfl_xor(rsum, 1);
            rsum += __shfl_xor(rsum, 2);
            rsum += __shfl_xor(rsum, 4);
            rsum += __shfl_xor(rsum, 8);
            l_s[mi][r] = rsum;
        }

    __syncthreads();   // barrier 2: A16 free for P

    // ---- PV in 4 chunks of 64 t ----
    f32x4 oacc[2][4];
#pragma unroll
    for (int mi = 0; mi < 2; ++mi)
#pragma unroll
        for (int ne = 0; ne < 4; ++ne) {
            oacc[mi][ne][0] = 0.f; oacc[mi][ne][1] = 0.f;
            oacc[mi][ne][2] = 0.f; oacc[mi][ne][3] = 0.f;
        }

    for (int c = 0; c < 4; ++c) {
#pragma unroll
        for (int j = 0; j < 4; ++j)
#pragma unroll
            for (int mi = 0; mi < 2; ++mi)
#pragma unroll
                for (int r = 0; r < 4; ++r) {
                    int row = r0 + mi * 16 + l4 * 4 + r;
                    A16[row * 64 + ((j * 16 + l16) ^ ((row & 7) << 3))] = f2bf(sa[mi][c * 4 + j][r]);
                }
        bf16x8 pa[2][2];
#pragma unroll
        for (int mi = 0; mi < 2; ++mi)
#pragma unroll
            for (int kk = 0; kk < 2; ++kk) {
                int row = r0 + mi * 16 + l16;
                pa[mi][kk] = *(const bf16x8*)&A16[row * 64 + ((kk * 32 + l4 * 8) ^ ((row & 7) << 3))];
            }
#pragma unroll
        for (int ne = 0; ne < 4; ++ne) {
            int e = ne * 16 + l16;
            bf16x8 v0 = *(const bf16x8*)&B16[e * 256 + ((c * 64 + l4 * 8) ^ ((e & 7) << 3))];
            bf16x8 v1 = *(const bf16x8*)&B16[e * 256 + ((c * 64 + 32 + l4 * 8) ^ ((e & 7) << 3))];
#pragma unroll
            for (int mi = 0; mi < 2; ++mi) {
                oacc[mi][ne] = __builtin_amdgcn_mfma_f32_16x16x32_bf16(pa[mi][0], v0, oacc[mi][ne], 0, 0, 0);
                oacc[mi][ne] = __builtin_amdgcn_mfma_f32_16x16x32_bf16(pa[mi][1], v1, oacc[mi][ne], 0, 0, 0);
            }
        }
    }

    // ---- epilogue: O staged across whole 64KB -> coalesced residual ----
    __syncthreads();   // barrier 3
    float* Osm = (float*)sm + wave * 2048;
#pragma unroll
    for (int mi = 0; mi < 2; ++mi)
#pragma unroll
        for (int r = 0; r < 4; ++r) {
            float inv = 1.0f / l_s[mi][r];
            int rl = mi * 16 + l4 * 4 + r;
#pragma unroll
            for (int ne = 0; ne < 4; ++ne)
                Osm[rl * 64 + ((ne * 16 + l16) ^ ((rl & 3) << 4))] = oacc[mi][ne][r] * inv;
        }
    float psum = 0.f, psq = 0.f;
#pragma unroll
    for (int it = 0; it < 8; ++it) {
        int rl = it * 4 + l4;
        int row = r0 + rl;
        if (row < SEQL) {
            size_t off = ((size_t)b * SEQL + row) * HD + h * 64 + l16 * 4;
            float4 ov = *(float4*)&Osm[rl * 64 + ((l16 * 4) ^ ((rl & 3) << 4))];
            float4 tv = *(const float4*)&tok[off];
            float4 o;
            o.x = ov.x + tv.x; o.y = ov.y + tv.y;
            o.z = ov.z + tv.z; o.w = ov.w + tv.w;
            *(float4*)&out[off] = o;
            psum += o.x + o.y + o.z + o.w;
            psq  += o.x * o.x + o.y * o.y + o.z * o.z + o.w * o.w;
        }
    }
#pragma unroll
    for (int off = 32; off > 0; off >>= 1) {
        psum += __shfl_down(psum, off);
        psq += __shfl_down(psq, off);
    }
    if (lane == 0) { rS[wave] = psum; rS2[wave] = psq; }
    __syncthreads();
    if (tid == 0) {
        float S = 0.f, S2 = 0.f;
#pragma unroll
        for (int i = 0; i < 8; ++i) { S += rS[i]; S2 += rS2[i]; }
        atomicAdd(&stats[128 + 2 * b], S);
        atomicAdd(&stats[129 + 2 * b], S2);
    }
#undef PROJ_ACC
#undef ZERO_ACC
}

// ---------------- LN2 apply (finalizes stats from raw sums) -> bf16 ----------------
__global__ void k_ln2apply(const float* __restrict__ outb, const float* __restrict__ stats,
                           const float* __restrict__ g2, const float* __restrict__ b2,
                           ushort_t* __restrict__ x) {
    int i = blockIdx.x * 256 + threadIdx.x;
    if (i >= BATCH * SEQL * HD / 4) return;
    int e4 = i * 4;
    int m = e4 / HD, kk = e4 % HD;
    int b = m / SEQL, s = m % SEQL;
    const float inv_n = 1.0f / (float)(SEQL * HD);
    float S = stats[128 + 2 * b], S2 = stats[129 + 2 * b];
    float mu = S * inv_n;
    float rsg = rsqrtf(S2 * inv_n - mu * mu + 1e-5f);
    float4 t = *(const float4*)&outb[e4];
    float4 g = *(const float4*)&g2[s * HD + kk];
    float4 bb = *(const float4*)&b2[s * HD + kk];
    ushort4 o;
    o.x = f2bf((t.x - mu) * rsg * g.x + bb.x);
    o.y = f2bf((t.y - mu) * rsg * g.y + bb.y);
    o.z = f2bf((t.z - mu) * rsg * g.z + bb.z);
    o.w = f2bf((t.w - mu) * rsg * g.w + bb.w);
    *(ushort4*)&x[e4] = o;
}

// ---------------- classifier logits: partial dots over e-chunks (4x parallel) ----
__launch_bounds__(256)
__global__ void k_logits(const float* __restrict__ out, const float* __restrict__ Wo,
                         float* __restrict__ logits) {
    const int eg = blockIdx.x, b = blockIdx.y, tid = threadIdx.x;
    __shared__ float cls[192];
    if (tid < 48)
        *(float4*)&cls[tid * 4] = *(const float4*)&out[(size_t)(b * SEQL) * HD + eg * 192 + tid * 4];
    __syncthreads();
    const int o0 = tid * 4;
    if (o0 < OUTD) {
        float4 acc = {0.f, 0.f, 0.f, 0.f};
        const float* wbase = &Wo[(size_t)eg * 192 * OUTD + o0];
#pragma unroll 4
        for (int e = 0; e < 192; ++e) {
            float c = cls[e];
            float4 w = *(const float4*)&wbase[(size_t)e * OUTD];
            acc.x += c * w.x;
            acc.y += c * w.y;
            acc.z += c * w.z;
            acc.w += c * w.w;
        }
        atomicAdd(&logits[b * OUTD + o0 + 0], acc.x);
        atomicAdd(&logits[b * OUTD + o0 + 1], acc.y);
        atomicAdd(&logits[b * OUTD + o0 + 2], acc.z);
        atomicAdd(&logits[b * OUTD + o0 + 3], acc.w);
    }
}

// ---------------- head softmax (reads logits + bias) ----------------
__launch_bounds__(256)
__global__ void k_head_sm(const float* __restrict__ logits, const float* __restrict__ bo,
                          float* __restrict__ dout) {
    const int b = blockIdx.x, tid = threadIdx.x;
    __shared__ float red[256];
    const int o0 = tid * 4;
    const bool ok = (o0 < OUTD);
    float4 acc = {0.f, 0.f, 0.f, 0.f};
    if (ok) {
        float4 lg = *(const float4*)&logits[b * OUTD + o0];
        float4 bb = *(const float4*)&bo[o0];
        acc.x = lg.x + bb.x; acc.y = lg.y + bb.y;
        acc.z = lg.z + bb.z; acc.w = lg.w + bb.w;
    }
    float mx = ok ? fmaxf(fmaxf(acc.x, acc.y), fmaxf(acc.z, acc.w)) : -INFINITY;
    red[tid] = mx;
    __syncthreads();
    for (int s = 128; s > 0; s >>= 1) {
        if (tid < s) red[tid] = fmaxf(red[tid], red[tid + s]);
        __syncthreads();
    }
    float M = red[0];
    __syncthreads();
    float4 p = {0.f, 0.f, 0.f, 0.f};
    float ls = 0.f;
    if (ok) {
        p.x = expf(acc.x - M);
        p.y = expf(acc.y - M);
        p.z = expf(acc.z - M);
        p.w = expf(acc.w - M);
        ls = p.x + p.y + p.z + p.w;
    }
    red[tid] = ls;
    __syncthreads();
    for (int s = 128; s > 0; s >>= 1) {
        if (tid < s) red[tid] += red[tid + s];
        __syncthreads();
    }
    float inv = 1.0f / red[0];
    if (ok) {
        p.x *= inv; p.y *= inv; p.z *= inv; p.w *= inv;
        *(float4*)&dout[b * OUTD + o0] = p;
    }
}

extern "C" void kernel_launch(void* const* d_in, const int* in_sizes, int n_in,
                              void* d_out, int out_size, void* d_ws, size_t ws_size,
                              hipStream_t stream) {
    const float* images  = (const float*)d_in[0];
    const float* W_map   = (const float*)d_in[1];
    const float* b_map   = (const float*)d_in[2];
    const float* cls_tok = (const float*)d_in[3];
    const float* ln1_g   = (const float*)d_in[4];
    const float* ln1_b   = (const float*)d_in[5];
    const float* Wq      = (const float*)d_in[6];
    const float* bq      = (const float*)d_in[7];
    const float* Wk      = (const float*)d_in[8];
    const float* bk      = (const float*)d_in[9];
    const float* Wv      = (const float*)d_in[10];
    const float* bv      = (const float*)d_in[11];
    const float* ln2_g   = (const float*)d_in[12];
    const float* ln2_b   = (const float*)d_in[13];
    const float* W_enc   = (const float*)d_in[14];
    const float* b_enc   = (const float*)d_in[15];
    const float* W_out   = (const float*)d_in[16];
    const float* b_out   = (const float*)d_in[17];

    float* ws = (float*)d_ws;
    const size_t BIG = (size_t)BATCH * SEQL * HD;     // 9,682,944

    float* pos   = ws;
    float* tok   = ws + 151552;
    float* outb  = tok + BIG;
    float* stats = outb + BIG;                        // 512 f32: LN1 raw | LN2 raw | cls sums @256
    ushort_t* wtq = (ushort_t*)(stats + 512);         // bf16 147,456
    ushort_t* Ae  = wtq + 147456;                     // bf16 [12672][768]
    ushort_t* WmT = Ae + (size_t)12672 * 768;         // bf16 [768][768]
    ushort_t* WeT = WmT + (size_t)768 * 768;          // bf16 [768][768]
    float* logits = (float*)(WeT + (size_t)768 * 768);// 64,000 f32
    ushort_t* Ae2 = Ae;

    k_prep<<<11488, 256, 0, stream>>>(W_map, W_enc, Wq, Wk, Wv, cls_tok, images,
                                      WmT, WeT, wtq, stats, logits, pos, tok, Ae);
    k_gemm_bf16<0><<<588, 256, 0, stream>>>(Ae, WmT, b_map, pos, tok, 12544, stats, 588);
    k_qkvattn<<<dim3(12, 64), 512, 0, stream>>>(tok, stats, ln1_g, ln1_b, wtq, bq, bk, bv, outb);
    k_ln2apply<<<9456, 256, 0, stream>>>(outb, stats, ln2_g, ln2_b, Ae2);
    k_gemm_bf16<1><<<594, 256, 0, stream>>>(Ae2, WeT, b_enc, pos, outb, 12608, stats, 594);
    k_logits<<<dim3(4, 64), 256, 0, stream>>>(outb, W_out, logits);
    k_head_sm<<<64, 256, 0, stream>>>(logits, b_out, (float*)d_out);
}

// Round 19
// 233.139 us; speedup vs baseline: 1.2680x; 1.0029x over previous
//
#include <hip/hip_runtime.h>
#include <math.h>

#define SEQL 197
#define HD 768
#define NH 12
#define DHD 64
#define BATCH 64
#define OUTD 1000

typedef unsigned short ushort_t;
typedef __attribute__((ext_vector_type(8))) short bf16x8;
typedef __attribute__((ext_vector_type(4))) float f32x4;

static __device__ __forceinline__ unsigned short f2bf(float f) {
    union { float f; unsigned u; } v; v.f = f;
    unsigned r = v.u + 0x7fff + ((v.u >> 16) & 1);
    return (unsigned short)(r >> 16);
}

static __device__ __forceinline__ void gload16(const ushort_t* g, ushort_t* l) {
    __builtin_amdgcn_global_load_lds(
        (const __attribute__((address_space(1))) unsigned int*)g,
        (__attribute__((address_space(3))) unsigned int*)l, 16, 0, 0);
}

// bijective XCD-chunk swizzle (m204) — used by the GEMMs only (A-panel L2 reuse).
static __device__ __forceinline__ int xcd_chunk(int id, int nwg) {
    int xcd = id & 7, ii = id >> 3;
    int q = nwg >> 3, r = nwg & 7;
    return (xcd < r) ? (xcd * (q + 1) + ii) : (r * (q + 1) + (xcd - r) * q + ii);
}

// ---------------- merged prologue: weight cvts + zeroing + pos/cls + patches ----
// block ranges: [0,1296) cvt+zero | [1296,2079) pos/cls | 2079 S_cls | [2080,11488) patches
#define NB_CVT  1296
#define NB_INIT 783
__global__ void k_prep(const float* __restrict__ W_map, const float* __restrict__ W_enc,
                       const float* __restrict__ Wq, const float* __restrict__ Wk,
                       const float* __restrict__ Wv, const float* __restrict__ cls_tok,
                       const float* __restrict__ img,
                       ushort_t* __restrict__ WmT, ushort_t* __restrict__ WeT,
                       ushort_t* __restrict__ wt, float* __restrict__ stats,
                       float* __restrict__ logits, float* __restrict__ pos,
                       float* __restrict__ tok, ushort_t* __restrict__ Ae) {
    const int bx = blockIdx.x, tid = threadIdx.x;
    if (bx < NB_CVT) {
        int idx = bx * 256 + tid;
        if (bx == 0) { stats[tid] = 0.f; }                 // zero stats[0..256)
        if (idx < BATCH * OUTD) logits[idx] = 0.f;
        if (idx < 2 * 147456) {
            const float* W = (idx < 147456) ? W_map : W_enc;
            ushort_t* WT   = (idx < 147456) ? WmT : WeT;
            int i = (idx < 147456) ? idx : idx - 147456;
            int k = i / 192, nq = i % 192;
            float4 w = *(const float4*)&W[k * 768 + nq * 4];
            WT[(nq * 4 + 0) * 768 + k] = f2bf(w.x);
            WT[(nq * 4 + 1) * 768 + k] = f2bf(w.y);
            WT[(nq * 4 + 2) * 768 + k] = f2bf(w.z);
            WT[(nq * 4 + 3) * 768 + k] = f2bf(w.w);
        } else {
            int i = idx - 2 * 147456;
            if (i < 36864) {
                int dq = i & 15;
                int e  = (i >> 4) & 63;
                int h  = (i >> 10) % 12;
                int pj = i / 12288;
                const float* W = (pj == 0) ? Wq : (pj == 1) ? Wk : Wv;
                ushort4 o;
                o.x = f2bf(W[(h * 64 + dq * 4 + 0) * 64 + e]);
                o.y = f2bf(W[(h * 64 + dq * 4 + 1) * 64 + e]);
                o.z = f2bf(W[(h * 64 + dq * 4 + 2) * 64 + e]);
                o.w = f2bf(W[(h * 64 + dq * 4 + 3) * 64 + e]);
                *(ushort4*)&wt[(size_t)((pj * 12 + h) * 64 + e) * 64 + dq * 4] = o;
            }
        }
    } else if (bx < NB_CVT + NB_INIT) {
        int i = (bx - NB_CVT) * 256 + tid;
        if (i < SEQL * HD) {
            int s = i / HD, d = i % HD;
            float f = (float)(d & ~1);
            float r = powf(10000.0f, -f / (float)HD);
            float a = (float)s * r;
            pos[i] = (d & 1) ? cosf(a) : sinf(a);
        } else {
            int j = i - SEQL * HD;   // < BATCH*HD by construction (783*256 = 200448)
            int b = j / HD, e = j % HD;
            tok[(b * SEQL) * HD + e] = cls_tok[e] + ((e & 1) ? 1.0f : 0.0f);
        }
    } else if (bx == NB_CVT + NB_INIT) {
        // batch-invariant cls-row LN1 sums -> stats[256], stats[257]
        __shared__ float rs[4], rs2[4];
        float s = 0.f, s2 = 0.f;
#pragma unroll
        for (int j = 0; j < 3; ++j) {
            int e = tid * 3 + j;
            float v = cls_tok[e] + ((e & 1) ? 1.0f : 0.0f);
            s += v; s2 += v * v;
        }
#pragma unroll
        for (int off = 32; off > 0; off >>= 1) {
            s += __shfl_down(s, off);
            s2 += __shfl_down(s2, off);
        }
        int lane = tid & 63, w = tid >> 6;
        if (lane == 0) { rs[w] = s; rs2[w] = s2; }
        __syncthreads();
        if (tid == 0) {
            float S = 0.f, S2 = 0.f;
#pragma unroll
            for (int i = 0; i < 4; ++i) { S += rs[i]; S2 += rs2[i]; }
            stats[256] = S;
            stats[257] = S2;
        }
    } else {
        int idx = (bx - (NB_CVT + NB_INIT + 1)) * 256 + tid;   // patches
        int m = idx / 192, kq = idx % 192;
        int k0 = kq * 4;
        int c = k0 >> 8, rem = k0 & 255, ir = rem >> 4, jc = rem & 15;
        int b = m / 196, pi = m % 196;
        int pr = pi / 14, pc = pi % 14;
        float4 v = *(const float4*)&img[((b * 3 + c) * 224 + pr * 16 + ir) * 224 + pc * 16 + jc];
        ushort4 o;
        o.x = f2bf(v.x); o.y = f2bf(v.y); o.z = f2bf(v.z); o.w = f2bf(v.w);
        *(ushort4*)&Ae[m * 768 + k0] = o;
    }
}

// ---------------- bf16 MFMA GEMM, 128x128 tile, BK=64, 4 waves -----------------
// T3 minimum 2-phase: double-buffered LDS; next-tile global_load_lds issued
// BEFORE this tile's ds_read+MFMA; single barrier per K-step (its implicit
// vmcnt(0) drain is the "next tile ready" sync). XCD-chunked grid.
template <int MODE>
__launch_bounds__(256)
__global__ void k_gemm_bf16(const ushort_t* __restrict__ A, const ushort_t* __restrict__ Bt,
                            const float* __restrict__ bias, const float* __restrict__ pos,
                            float* __restrict__ out, int Mtot, float* __restrict__ stats,
                            int nwg) {
    __shared__ ushort_t As[2][128 * 64];
    __shared__ ushort_t Bs[2][128 * 64];
    __shared__ float redS[4][4];
    const int vid = xcd_chunk(blockIdx.x, nwg);
    const int m0 = (vid / 6) * 128;
    const int n0 = (vid % 6) * 128;
    const int tid = threadIdx.x;
    const int lane = tid & 63, wave = tid >> 6;
    const int wm = wave >> 1, wn = wave & 1;

    // per-thread staging geometry (constant across K-steps)
    int stg_c[4], stg_row[4], stg_col[4];
#pragma unroll
    for (int t = 0; t < 4; ++t) {
        int c = (wave << 2) | t;
        int o = c * 1024 + lane * 16;
        int row = o >> 7;
        int inner = o & 127;
        stg_c[t] = c;
        stg_row[t] = row;
        stg_col[t] = (inner ^ ((row & 7) << 4)) >> 1;
    }

#define STAGE(BUF, K0)                                                                    \
    {                                                                                     \
        _Pragma("unroll") for (int t = 0; t < 4; ++t) {                                   \
            gload16(&A[(size_t)(m0 + stg_row[t]) * 768 + (K0) + stg_col[t]],              \
                    &As[BUF][stg_c[t] * 512]);                                            \
            gload16(&Bt[(size_t)(n0 + stg_row[t]) * 768 + (K0) + stg_col[t]],             \
                    &Bs[BUF][stg_c[t] * 512]);                                            \
        }                                                                                 \
    }

    f32x4 acc[4][4];
#pragma unroll
    for (int i = 0; i < 4; ++i)
#pragma unroll
        for (int j = 0; j < 4; ++j)
#pragma unroll
            for (int r = 0; r < 4; ++r) acc[i][j][r] = 0.f;

    // prologue: stage tile 0
    STAGE(0, 0);
    __syncthreads();

    int cur = 0;
    for (int kt = 0; kt < 12; ++kt) {
        // issue next tile's loads first (they fly under this tile's MFMAs)
        if (kt < 11) STAGE(cur ^ 1, (kt + 1) * 64);

#pragma unroll
        for (int ks = 0; ks < 2; ++ks) {
            const int cbyte = ks * 64 + (lane >> 4) * 16;
            bf16x8 af[4], bf[4];
#pragma unroll
            for (int mi = 0; mi < 4; ++mi) {
                int row = wm * 64 + mi * 16 + (lane & 15);
                af[mi] = *(const bf16x8*)((const char*)&As[cur][0] + row * 128 + (cbyte ^ ((row & 7) << 4)));
            }
#pragma unroll
            for (int ni = 0; ni < 4; ++ni) {
                int n = wn * 64 + ni * 16 + (lane & 15);
                bf[ni] = *(const bf16x8*)((const char*)&Bs[cur][0] + n * 128 + (cbyte ^ ((n & 7) << 4)));
            }
#pragma unroll
            for (int mi = 0; mi < 4; ++mi)
#pragma unroll
                for (int ni = 0; ni < 4; ++ni)
                    acc[mi][ni] = __builtin_amdgcn_mfma_f32_16x16x32_bf16(af[mi], bf[ni], acc[mi][ni], 0, 0, 0);
        }
        __syncthreads();   // drains next-tile loads (vmcnt 0) + guards buffer reuse
        cur ^= 1;
    }
#undef STAGE

    const int colb = n0 + wn * 64 + (lane & 15);
    const int rowb = m0 + wm * 64 + (lane >> 4) * 4;
    float s_lo = 0.f, q_lo = 0.f, s_hi = 0.f, q_hi = 0.f;
    const int bA = m0 / 196;
    const int mSplit = (bA + 1) * 196;
#pragma unroll
    for (int ni = 0; ni < 4; ++ni) {
        const int n = colb + ni * 16;
        const float bn = bias[n];
#pragma unroll
        for (int mi = 0; mi < 4; ++mi) {
#pragma unroll
            for (int r = 0; r < 4; ++r) {
                int m = rowb + mi * 16 + r;
                if (MODE == 0) {
                    int b = m / 196, s = 1 + m % 196;
                    float oval = acc[mi][ni][r] + bn + pos[s * HD + n];
                    out[((b * SEQL) + s) * HD + n] = oval;
                    if (m < mSplit) { s_lo += oval; q_lo += oval * oval; }
                    else            { s_hi += oval; q_hi += oval * oval; }
                } else {
                    if (m < Mtot) {
                        float* p = &out[(size_t)m * HD + n];
                        *p = *p + fmaxf(acc[mi][ni][r] + bn, 0.f);
                    }
                }
            }
        }
    }
    if (MODE == 0) {
#pragma unroll
        for (int off = 32; off > 0; off >>= 1) {
            s_lo += __shfl_down(s_lo, off);
            q_lo += __shfl_down(q_lo, off);
            s_hi += __shfl_down(s_hi, off);
            q_hi += __shfl_down(q_hi, off);
        }
        if (lane == 0) {
            redS[wave][0] = s_lo; redS[wave][1] = q_lo;
            redS[wave][2] = s_hi; redS[wave][3] = q_hi;
        }
        __syncthreads();
        if (tid == 0) {
            float a0 = 0.f, a1 = 0.f, a2 = 0.f, a3 = 0.f;
#pragma unroll
            for (int i = 0; i < 4; ++i) {
                a0 += redS[i][0]; a1 += redS[i][1];
                a2 += redS[i][2]; a3 += redS[i][3];
            }
            atomicAdd(&stats[2 * bA], a0);
            atomicAdd(&stats[2 * bA + 1], a1);
            int bB = bA + 1;
            if (bB < BATCH) {
                atomicAdd(&stats[2 * bB], a2);
                atomicAdd(&stats[2 * bB + 1], a3);
            }
        }
    }
}

// ---------------- FUSED: LN1 + QKV + attention + residual (round-15 body) ------
// grid dim3(12,64), default dispatch order (h-major) — best measured tok locality.
__launch_bounds__(512, 2)
__global__ void k_qkvattn(const float* __restrict__ tok, float* __restrict__ stats,
                          const float* __restrict__ g1, const float* __restrict__ b1,
                          const ushort_t* __restrict__ wt,
                          const float* __restrict__ bq, const float* __restrict__ bk,
                          const float* __restrict__ bv, float* __restrict__ out) {
    const int h = blockIdx.x, b = blockIdx.y;
    __shared__ __attribute__((aligned(16))) ushort_t sm[32768];   // A16 | B16
    __shared__ float rS[8], rS2[8];
    const int tid = threadIdx.x;
    const int wave = tid >> 6, lane = tid & 63;
    const int l16 = lane & 15, l4 = lane >> 4;
    const int r0 = wave * 32;
    const float inv_n = 1.0f / (float)(SEQL * HD);
    const float S1_ = stats[b * 2] + stats[256];      // patch sums + batch-invariant cls sums
    const float S2_ = stats[b * 2 + 1] + stats[257];
    const float mu = S1_ * inv_n;
    const float rsg = rsqrtf(S2_ * inv_n - mu * mu + 1e-5f);
    ushort_t* A16 = sm;            // [256][64] XOR (X / Qtmp / K / P)
    ushort_t* B16 = sm + 16384;    // [64][256] XOR (V^T)

    // ---- stage LN1(X) into OWN A16 rows ----
    {
        const int row = tid >> 1, hw = tid & 1;
        if (row < SEQL) {
            const float* tp = &tok[((size_t)b * SEQL + row) * HD + h * 64 + hw * 32];
            const float* gp = &g1[(size_t)row * HD + h * 64 + hw * 32];
            const float* bp = &b1[(size_t)row * HD + h * 64 + hw * 32];
#pragma unroll
            for (int g = 0; g < 4; ++g) {
                float4 t0 = *(const float4*)&tp[g * 8];
                float4 t1 = *(const float4*)&tp[g * 8 + 4];
                float4 ga = *(const float4*)&gp[g * 8];
                float4 gb = *(const float4*)&gp[g * 8 + 4];
                float4 ba = *(const float4*)&bp[g * 8];
                float4 bb = *(const float4*)&bp[g * 8 + 4];
                bf16x8 o;
                o[0] = (short)f2bf((t0.x - mu) * rsg * ga.x + ba.x);
                o[1] = (short)f2bf((t0.y - mu) * rsg * ga.y + ba.y);
                o[2] = (short)f2bf((t0.z - mu) * rsg * ga.z + ba.z);
                o[3] = (short)f2bf((t0.w - mu) * rsg * ga.w + ba.w);
                o[4] = (short)f2bf((t1.x - mu) * rsg * gb.x + bb.x);
                o[5] = (short)f2bf((t1.y - mu) * rsg * gb.y + bb.y);
                o[6] = (short)f2bf((t1.z - mu) * rsg * gb.z + bb.z);
                o[7] = (short)f2bf((t1.w - mu) * rsg * gb.w + bb.w);
                int pc = (hw * 32 + g * 8) ^ ((row & 7) << 3);
                *(bf16x8*)&A16[row * 64 + pc] = o;
            }
        } else {
            bf16x8 z;
#pragma unroll
            for (int j = 0; j < 8; ++j) z[j] = 0;
#pragma unroll
            for (int g = 0; g < 4; ++g) {
                int pc = (hw * 32 + g * 8) ^ ((row & 7) << 3);
                *(bf16x8*)&A16[row * 64 + pc] = z;
            }
        }
    }

    // A fragments from own rows (wave-private; no barrier needed)
    bf16x8 af[2][2];
#pragma unroll
    for (int mi = 0; mi < 2; ++mi)
#pragma unroll
        for (int kk = 0; kk < 2; ++kk) {
            int row = r0 + mi * 16 + l16;
            af[mi][kk] = *(const bf16x8*)&A16[row * 64 + ((kk * 32 + l4 * 8) ^ ((row & 7) << 3))];
        }

#define PROJ_ACC(PJ, ACC)                                                                      \
    {                                                                                          \
        _Pragma("unroll") for (int ni = 0; ni < 4; ++ni) {                                     \
            const ushort_t* wr = &wt[(size_t)(((PJ) * 12 + h) * 64 + ni * 16 + l16) * 64];     \
            bf16x8 w0 = *(const bf16x8*)&wr[l4 * 8];                                           \
            bf16x8 w1 = *(const bf16x8*)&wr[32 + l4 * 8];                                      \
            _Pragma("unroll") for (int mi = 0; mi < 2; ++mi) {                                 \
                ACC[mi][ni] = __builtin_amdgcn_mfma_f32_16x16x32_bf16(af[mi][0], w0, ACC[mi][ni], 0, 0, 0); \
                ACC[mi][ni] = __builtin_amdgcn_mfma_f32_16x16x32_bf16(af[mi][1], w1, ACC[mi][ni], 0, 0, 0); \
            }                                                                                  \
        }                                                                                      \
    }

    f32x4 acc[2][4];
#define ZERO_ACC                                                                               \
    _Pragma("unroll") for (int mi = 0; mi < 2; ++mi)                                           \
        _Pragma("unroll") for (int ni = 0; ni < 4; ++ni) {                                     \
            acc[mi][ni][0] = 0.f; acc[mi][ni][1] = 0.f; acc[mi][ni][2] = 0.f; acc[mi][ni][3] = 0.f; }

    // ---- Q projection -> Qtmp bounce in OWN A16 rows ----
    ZERO_ACC;
    PROJ_ACC(0, acc);
#pragma unroll
    for (int ni = 0; ni < 4; ++ni) {
        float bn = bq[h * 64 + ni * 16 + l16];
#pragma unroll
        for (int mi = 0; mi < 2; ++mi)
#pragma unroll
            for (int r = 0; r < 4; ++r) {
                int row = r0 + mi * 16 + l4 * 4 + r;
                A16[row * 64 + ((ni * 16 + l16) ^ ((row & 7) << 3))] = f2bf(acc[mi][ni][r] + bn);
            }
    }
    bf16x8 qa[2][2];
#pragma unroll
    for (int mi = 0; mi < 2; ++mi)
#pragma unroll
        for (int kk = 0; kk < 2; ++kk) {
            int row = r0 + mi * 16 + l16;
            qa[mi][kk] = *(const bf16x8*)&A16[row * 64 + ((kk * 32 + l4 * 8) ^ ((row & 7) << 3))];
        }

    // ---- K projection -> OWN A16 rows ----
    ZERO_ACC;
    PROJ_ACC(1, acc);
#pragma unroll
    for (int ni = 0; ni < 4; ++ni) {
        float bn = bk[h * 64 + ni * 16 + l16];
#pragma unroll
        for (int mi = 0; mi < 2; ++mi)
#pragma unroll
            for (int r = 0; r < 4; ++r) {
                int t = r0 + mi * 16 + l4 * 4 + r;
                A16[t * 64 + ((ni * 16 + l16) ^ ((t & 7) << 3))] = f2bf(acc[mi][ni][r] + bn);
            }
    }

    // ---- V projection -> B16 (transposed, XOR, packed) ----
    ZERO_ACC;
    PROJ_ACC(2, acc);
#pragma unroll
    for (int ni = 0; ni < 4; ++ni) {
        float bn = bv[h * 64 + ni * 16 + l16];
#pragma unroll
        for (int mi = 0; mi < 2; ++mi) {
            int t4 = r0 + mi * 16 + l4 * 4;
            int e = ni * 16 + l16;
            ushort4 pkt;
            pkt.x = f2bf(acc[mi][ni][0] + bn);
            pkt.y = f2bf(acc[mi][ni][1] + bn);
            pkt.z = f2bf(acc[mi][ni][2] + bn);
            pkt.w = f2bf(acc[mi][ni][3] + bn);
            *(ushort4*)&B16[e * 256 + (t4 ^ ((e & 7) << 3))] = pkt;
        }
    }

    __syncthreads();   // barrier 1: K and V^T visible

    // ---- QK^T over all 256 t ----
    f32x4 sa[2][16];
#pragma unroll
    for (int ni = 0; ni < 16; ++ni) {
        int t = ni * 16 + l16;
        bf16x8 k0 = *(const bf16x8*)&A16[t * 64 + ((l4 * 8) ^ ((t & 7) << 3))];
        bf16x8 k1 = *(const bf16x8*)&A16[t * 64 + ((32 + l4 * 8) ^ ((t & 7) << 3))];
#pragma unroll
        for (int mi = 0; mi < 2; ++mi) {
            f32x4 z;
            z[0] = 0.f; z[1] = 0.f; z[2] = 0.f; z[3] = 0.f;
            z = __builtin_amdgcn_mfma_f32_16x16x32_bf16(qa[mi][0], k0, z, 0, 0, 0);
            sa[mi][ni] = __builtin_amdgcn_mfma_f32_16x16x32_bf16(qa[mi][1], k1, z, 0, 0, 0);
        }
    }

    // ---- softmax per q-row, NO max subtraction ----
    float l_s[2][4];
#pragma unroll
    for (int mi = 0; mi < 2; ++mi)
#pragma unroll
        for (int r = 0; r < 4; ++r) {
            float rsum = 0.f;
#pragma unroll
            for (int ni = 0; ni < 16; ++ni) {
                float p = (ni * 16 + l16 < SEQL) ? __expf(sa[mi][ni][r] * 0.125f) : 0.f;
                sa[mi][ni][r] = p;
                rsum += p;
            }
            rsum += __shfl_xor(rsum, 1);
            rsum += __shfl_xor(rsum, 2);
            rsum += __shfl_xor(rsum, 4);
            rsum += __shfl_xor(rsum, 8);
            l_s[mi][r] = rsum;
        }

    __syncthreads();   // barrier 2: A16 free for P

    // ---- PV in 4 chunks of 64 t ----
    f32x4 oacc[2][4];
#pragma unroll
    for (int mi = 0; mi < 2; ++mi)
#pragma unroll
        for (int ne = 0; ne < 4; ++ne) {
            oacc[mi][ne][0] = 0.f; oacc[mi][ne][1] = 0.f;
            oacc[mi][ne][2] = 0.f; oacc[mi][ne][3] = 0.f;
        }

    for (int c = 0; c < 4; ++c) {
#pragma unroll
        for (int j = 0; j < 4; ++j)
#pragma unroll
            for (int mi = 0; mi < 2; ++mi)
#pragma unroll
                for (int r = 0; r < 4; ++r) {
                    int row = r0 + mi * 16 + l4 * 4 + r;
                    A16[row * 64 + ((j * 16 + l16) ^ ((row & 7) << 3))] = f2bf(sa[mi][c * 4 + j][r]);
                }
        bf16x8 pa[2][2];
#pragma unroll
        for (int mi = 0; mi < 2; ++mi)
#pragma unroll
            for (int kk = 0; kk < 2; ++kk) {
                int row = r0 + mi * 16 + l16;
                pa[mi][kk] = *(const bf16x8*)&A16[row * 64 + ((kk * 32 + l4 * 8) ^ ((row & 7) << 3))];
            }
#pragma unroll
        for (int ne = 0; ne < 4; ++ne) {
            int e = ne * 16 + l16;
            bf16x8 v0 = *(const bf16x8*)&B16[e * 256 + ((c * 64 + l4 * 8) ^ ((e & 7) << 3))];
            bf16x8 v1 = *(const bf16x8*)&B16[e * 256 + ((c * 64 + 32 + l4 * 8) ^ ((e & 7) << 3))];
#pragma unroll
            for (int mi = 0; mi < 2; ++mi) {
                oacc[mi][ne] = __builtin_amdgcn_mfma_f32_16x16x32_bf16(pa[mi][0], v0, oacc[mi][ne], 0, 0, 0);
                oacc[mi][ne] = __builtin_amdgcn_mfma_f32_16x16x32_bf16(pa[mi][1], v1, oacc[mi][ne], 0, 0, 0);
            }
        }
    }

    // ---- epilogue: O staged across whole 64KB -> coalesced residual ----
    __syncthreads();   // barrier 3
    float* Osm = (float*)sm + wave * 2048;
#pragma unroll
    for (int mi = 0; mi < 2; ++mi)
#pragma unroll
        for (int r = 0; r < 4; ++r) {
            float inv = 1.0f / l_s[mi][r];
            int rl = mi * 16 + l4 * 4 + r;
#pragma unroll
            for (int ne = 0; ne < 4; ++ne)
                Osm[rl * 64 + ((ne * 16 + l16) ^ ((rl & 3) << 4))] = oacc[mi][ne][r] * inv;
        }
    float psum = 0.f, psq = 0.f;
#pragma unroll
    for (int it = 0; it < 8; ++it) {
        int rl = it * 4 + l4;
        int row = r0 + rl;
        if (row < SEQL) {
            size_t off = ((size_t)b * SEQL + row) * HD + h * 64 + l16 * 4;
            float4 ov = *(float4*)&Osm[rl * 64 + ((l16 * 4) ^ ((rl & 3) << 4))];
            float4 tv = *(const float4*)&tok[off];
            float4 o;
            o.x = ov.x + tv.x; o.y = ov.y + tv.y;
            o.z = ov.z + tv.z; o.w = ov.w + tv.w;
            *(float4*)&out[off] = o;
            psum += o.x + o.y + o.z + o.w;
            psq  += o.x * o.x + o.y * o.y + o.z * o.z + o.w * o.w;
        }
    }
#pragma unroll
    for (int off = 32; off > 0; off >>= 1) {
        psum += __shfl_down(psum, off);
        psq += __shfl_down(psq, off);
    }
    if (lane == 0) { rS[wave] = psum; rS2[wave] = psq; }
    __syncthreads();
    if (tid == 0) {
        float S = 0.f, S2 = 0.f;
#pragma unroll
        for (int i = 0; i < 8; ++i) { S += rS[i]; S2 += rS2[i]; }
        atomicAdd(&stats[128 + 2 * b], S);
        atomicAdd(&stats[129 + 2 * b], S2);
    }
#undef PROJ_ACC
#undef ZERO_ACC
}

// ---------------- LN2 apply (finalizes stats from raw sums) -> bf16 ----------------
__global__ void k_ln2apply(const float* __restrict__ outb, const float* __restrict__ stats,
                           const float* __restrict__ g2, const float* __restrict__ b2,
                           ushort_t* __restrict__ x) {
    int i = blockIdx.x * 256 + threadIdx.x;
    if (i >= BATCH * SEQL * HD / 4) return;
    int e4 = i * 4;
    int m = e4 / HD, kk = e4 % HD;
    int b = m / SEQL, s = m % SEQL;
    const float inv_n = 1.0f / (float)(SEQL * HD);
    float S = stats[128 + 2 * b], S2 = stats[129 + 2 * b];
    float mu = S * inv_n;
    float rsg = rsqrtf(S2 * inv_n - mu * mu + 1e-5f);
    float4 t = *(const float4*)&outb[e4];
    float4 g = *(const float4*)&g2[s * HD + kk];
    float4 bb = *(const float4*)&b2[s * HD + kk];
    ushort4 o;
    o.x = f2bf((t.x - mu) * rsg * g.x + bb.x);
    o.y = f2bf((t.y - mu) * rsg * g.y + bb.y);
    o.z = f2bf((t.z - mu) * rsg * g.z + bb.z);
    o.w = f2bf((t.w - mu) * rsg * g.w + bb.w);
    *(ushort4*)&x[e4] = o;
}

// ---------------- classifier logits: partial dots over e-chunks (4x parallel) ----
__launch_bounds__(256)
__global__ void k_logits(const float* __restrict__ out, const float* __restrict__ Wo,
                         float* __restrict__ logits) {
    const int eg = blockIdx.x, b = blockIdx.y, tid = threadIdx.x;
    __shared__ float cls[192];
    if (tid < 48)
        *(float4*)&cls[tid * 4] = *(const float4*)&out[(size_t)(b * SEQL) * HD + eg * 192 + tid * 4];
    __syncthreads();
    const int o0 = tid * 4;
    if (o0 < OUTD) {
        float4 acc = {0.f, 0.f, 0.f, 0.f};
        const float* wbase = &Wo[(size_t)eg * 192 * OUTD + o0];
#pragma unroll 4
        for (int e = 0; e < 192; ++e) {
            float c = cls[e];
            float4 w = *(const float4*)&wbase[(size_t)e * OUTD];
            acc.x += c * w.x;
            acc.y += c * w.y;
            acc.z += c * w.z;
            acc.w += c * w.w;
        }
        atomicAdd(&logits[b * OUTD + o0 + 0], acc.x);
        atomicAdd(&logits[b * OUTD + o0 + 1], acc.y);
        atomicAdd(&logits[b * OUTD + o0 + 2], acc.z);
        atomicAdd(&logits[b * OUTD + o0 + 3], acc.w);
    }
}

// ---------------- head softmax (reads logits + bias) ----------------
__launch_bounds__(256)
__global__ void k_head_sm(const float* __restrict__ logits, const float* __restrict__ bo,
                          float* __restrict__ dout) {
    const int b = blockIdx.x, tid = threadIdx.x;
    __shared__ float red[256];
    const int o0 = tid * 4;
    const bool ok = (o0 < OUTD);
    float4 acc = {0.f, 0.f, 0.f, 0.f};
    if (ok) {
        float4 lg = *(const float4*)&logits[b * OUTD + o0];
        float4 bb = *(const float4*)&bo[o0];
        acc.x = lg.x + bb.x; acc.y = lg.y + bb.y;
        acc.z = lg.z + bb.z; acc.w = lg.w + bb.w;
    }
    float mx = ok ? fmaxf(fmaxf(acc.x, acc.y), fmaxf(acc.z, acc.w)) : -INFINITY;
    red[tid] = mx;
    __syncthreads();
    for (int s = 128; s > 0; s >>= 1) {
        if (tid < s) red[tid] = fmaxf(red[tid], red[tid + s]);
        __syncthreads();
    }
    float M = red[0];
    __syncthreads();
    float4 p = {0.f, 0.f, 0.f, 0.f};
    float ls = 0.f;
    if (ok) {
        p.x = expf(acc.x - M);
        p.y = expf(acc.y - M);
        p.z = expf(acc.z - M);
        p.w = expf(acc.w - M);
        ls = p.x + p.y + p.z + p.w;
    }
    red[tid] = ls;
    __syncthreads();
    for (int s = 128; s > 0; s >>= 1) {
        if (tid < s) red[tid] += red[tid + s];
        __syncthreads();
    }
    float inv = 1.0f / red[0];
    if (ok) {
        p.x *= inv; p.y *= inv; p.z *= inv; p.w *= inv;
        *(float4*)&dout[b * OUTD + o0] = p;
    }
}

extern "C" void kernel_launch(void* const* d_in, const int* in_sizes, int n_in,
                              void* d_out, int out_size, void* d_ws, size_t ws_size,
                              hipStream_t stream) {
    const float* images  = (const float*)d_in[0];
    const float* W_map   = (const float*)d_in[1];
    const float* b_map   = (const float*)d_in[2];
    const float* cls_tok = (const float*)d_in[3];
    const float* ln1_g   = (const float*)d_in[4];
    const float* ln1_b   = (const float*)d_in[5];
    const float* Wq      = (const float*)d_in[6];
    const float* bq      = (const float*)d_in[7];
    const float* Wk      = (const float*)d_in[8];
    const float* bk      = (const float*)d_in[9];
    const float* Wv      = (const float*)d_in[10];
    const float* bv      = (const float*)d_in[11];
    const float* ln2_g   = (const float*)d_in[12];
    const float* ln2_b   = (const float*)d_in[13];
    const float* W_enc   = (const float*)d_in[14];
    const float* b_enc   = (const float*)d_in[15];
    const float* W_out   = (const float*)d_in[16];
    const float* b_out   = (const float*)d_in[17];

    float* ws = (float*)d_ws;
    const size_t BIG = (size_t)BATCH * SEQL * HD;     // 9,682,944

    float* pos   = ws;
    float* tok   = ws + 151552;
    float* outb  = tok + BIG;
    float* stats = outb + BIG;                        // 512 f32: LN1 raw | LN2 raw | cls sums @256
    ushort_t* wtq = (ushort_t*)(stats + 512);         // bf16 147,456
    ushort_t* Ae  = wtq + 147456;                     // bf16 [12672][768]
    ushort_t* WmT = Ae + (size_t)12672 * 768;         // bf16 [768][768]
    ushort_t* WeT = WmT + (size_t)768 * 768;          // bf16 [768][768]
    float* logits = (float*)(WeT + (size_t)768 * 768);// 64,000 f32
    ushort_t* Ae2 = Ae;

    k_prep<<<11488, 256, 0, stream>>>(W_map, W_enc, Wq, Wk, Wv, cls_tok, images,
                                      WmT, WeT, wtq, stats, logits, pos, tok, Ae);
    k_gemm_bf16<0><<<588, 256, 0, stream>>>(Ae, WmT, b_map, pos, tok, 12544, stats, 588);
    k_qkvattn<<<dim3(12, 64), 512, 0, stream>>>(tok, stats, ln1_g, ln1_b, wtq, bq, bk, bv, outb);
    k_ln2apply<<<9456, 256, 0, stream>>>(outb, stats, ln2_g, ln2_b, Ae2);
    k_gemm_bf16<1><<<594, 256, 0, stream>>>(Ae2, WeT, b_enc, pos, outb, 12608, stats, 594);
    k_logits<<<dim3(4, 64), 256, 0, stream>>>(outb, W_out, logits);
    k_head_sm<<<64, 256, 0, stream>>>(logits, b_out, (float*)d_out);
}